// Round 6
// baseline (615.879 us; speedup 1.0000x reference)
//
#include <hip/hip_runtime.h>
#include <cstdint>
#include <cstddef>

// SAGE-LSTM R17: common-denominator cell update (7 trans vs 10).
// R16 post-mortem validated an instruction model: VALU issue = 141us/layer
// predicted vs 135us measured (VALUBusy 63% x 214us). Transcendentals (10 per
// element @ ~16cyc wave64 issue) are ~75% of VALU issue -> THE bottleneck.
// R17 folds the 5 sigmoid/tanh rcps into 2 via common denominators:
//   c' = [c(1+Ei)(1+Eg) + (1-Eg)(1+Ef)] * rcp((1+Ef)(1+Ei)(1+Eg))
//   h  = (1-Ec) * rcp((1+Eo)(1+Ec))          (E* = exp(-a), exp(-2a))
// 5 exp + 2 rcp = 7 trans/element; +7 cheap VALU. Overflow-safe (|gate|<~5,
// |c|<16 -> denom < ~5e8). Numerics identical to rcp accuracy; output is bf16.
// Everything else unchanged from verified R16.

constexpr int IN  = 128;
constexpr int DEG = 16;

typedef short bf16x8 __attribute__((ext_vector_type(8)));
typedef float f32x4  __attribute__((ext_vector_type(4)));
typedef float f32x16 __attribute__((ext_vector_type(16)));
typedef unsigned int u32x4 __attribute__((ext_vector_type(4)));
typedef unsigned int u32x2 __attribute__((ext_vector_type(2)));

__device__ __forceinline__ float fsigmoid(float x) {
    float e = __expf(-x);
    return __builtin_amdgcn_rcpf(1.0f + e);
}
__device__ __forceinline__ uint32_t pack2bf16(float a, float b) {
    uint32_t ua = __float_as_uint(a) + 0x8000u;
    uint32_t ub = __float_as_uint(b) + 0x8000u;
    return (ua >> 16) | (ub & 0xFFFF0000u);
}

// fused LSTM cell: 5 exp + 2 rcp. Updates c in place, returns h.
__device__ __forceinline__ float cell_h(float ai, float af, float ag, float ao,
                                        float& c) {
    float Ei = __expf(-ai);
    float Ef = __expf(-af);
    float Eg = __expf(-2.0f * ag);
    float Eo = __expf(-ao);
    float pi = 1.0f + Ei, pf = 1.0f + Ef, pg = 1.0f + Eg;
    float P1 = pi * pg;                       // (1+Ei)(1+Eg)
    float R1 = __builtin_amdgcn_rcpf(P1 * pf);
    float S  = __fmaf_rn(c, P1, (1.0f - Eg) * pf);
    float cv = S * R1;
    c = cv;
    float Ec = __expf(-2.0f * cv);
    float R2 = __builtin_amdgcn_rcpf((1.0f + Eo) * (1.0f + Ec));
    return (1.0f - Ec) * R2;
}

// ---------- prep kernels ----------

__global__ void k_cast_bf16(const float* __restrict__ src, ushort* __restrict__ dst, int n) {
    int i = (blockIdx.x * blockDim.x + threadIdx.x) * 4;
    if (i + 3 < n) {
        float4 v = *(const float4*)(src + i);
        uint2 d; d.x = pack2bf16(v.x, v.y); d.y = pack2bf16(v.z, v.w);
        *(uint2*)(dst + i) = d;
    } else {
        for (int k = i; k < n; ++k)
            dst[k] = (ushort)((__float_as_uint(src[k]) + 0x8000u) >> 16);
    }
}

// Pack all 4 [512 x 128] gate weights into MFMA fragment order.
// ih (which 0,2): 32x32x16 B-frag (consumed by k_xu).
// hh (which 1,3): 16x16x32 frag (A-operand in k_lstm_fused):
//   frag[((g*8+w)*4+ks)*64 + lane]; row jj = g*128+w*16+(lane&15),
//   k = ks*32+(lane>>4)*8+j.
__global__ void k_pack_all(const float* __restrict__ w0, u32x4* __restrict__ f0,
                           const float* __restrict__ w1, u32x4* __restrict__ f1,
                           const float* __restrict__ w2, u32x4* __restrict__ f2,
                           const float* __restrict__ w3, u32x4* __restrict__ f3) {
    int gt = blockIdx.x * 256 + threadIdx.x;     // 0..32767
    int which = gt >> 13;
    int tid  = gt & 8191;
    const float* wsrc = (which == 0) ? w0 : (which == 1) ? w1 : (which == 2) ? w2 : w3;
    u32x4* frag = (which == 0) ? f0 : (which == 1) ? f1 : (which == 2) ? f2 : f3;
    int lane = tid & 63;
    float v[8];
    if ((which & 1) == 0) {
        int tile = (tid >> 6) & 15;
        int kst  = tid >> 10;
        int n     = tile * 32 + (lane & 31);
        int kbase = kst * 16 + (lane >> 5) * 8;
#pragma unroll
        for (int j = 0; j < 8; ++j) v[j] = wsrc[n * 128 + kbase + j];
    } else {
        int f  = tid >> 6;            // 0..127
        int ks = f & 3;
        int w8 = (f >> 2) & 7;
        int g  = f >> 5;
        int jj    = g * 128 + w8 * 16 + (lane & 15);
        int kbase = ks * 32 + (lane >> 4) * 8;
#pragma unroll
        for (int j = 0; j < 8; ++j) v[j] = wsrc[jj * 128 + kbase + j];
    }
    u32x4 d;
    d.x = pack2bf16(v[0], v[1]);
    d.y = pack2bf16(v[2], v[3]);
    d.z = pack2bf16(v[4], v[5]);
    d.w = pack2bf16(v[6], v[7]);
    frag[tid] = d;
}

// Pack output-linear weights as A-frags over K=256 concat [Wself ; Wneigh].
__global__ void k_pack_out(const float* __restrict__ ws1, const float* __restrict__ wn1,
                           u32x4* __restrict__ f1,
                           const float* __restrict__ ws2, const float* __restrict__ wn2,
                           u32x4* __restrict__ f2) {
    int t = blockIdx.x * 256 + threadIdx.x;   // 0..6143
    int lane = t & 63;
    int row  = lane & 15;
    int kb   = (lane >> 4) * 8;
    float v[8];
    const float* ws; const float* wn; u32x4* dst; int p;
    if (t < 4096) { ws = ws1; wn = wn1; dst = f1; p = t; }
    else          { ws = ws2; wn = wn2; dst = f2; p = t - 4096; }
    int ks  = (p >> 6) & 7;
    int och = (p >> 9) * 16 + row;
    int kbase = ks * 32 + kb;
#pragma unroll
    for (int j = 0; j < 8; ++j) {
        int k = kbase + j;
        v[j] = (k < 128) ? ws[och * 128 + k] : wn[och * 128 + k - 128];
    }
    u32x4 d;
    d.x = pack2bf16(v[0], v[1]);
    d.y = pack2bf16(v[2], v[3]);
    d.z = pack2bf16(v[4], v[5]);
    d.w = pack2bf16(v[6], v[7]);
    dst[p] = d;
}

// ---------- kernel A: Xu = x @ W_ih^T + (b_ih+b_hh), gate-quad row store ----------
__global__ __launch_bounds__(256, 2) void k_xu(
    const ushort* __restrict__ x,       // [N,128] bf16
    const u32x4*  __restrict__ wih,     // 8192 B-frags (32x32 layout)
    const float*  __restrict__ b_ih,    // [512]
    const float*  __restrict__ b_hh,    // [512]
    u32x2*        __restrict__ xu,      // [Nceil][128] u32x2 (1KB rows)
    int N)
{
    __shared__ u32x4 a_buf[16][66];

    const int tid   = threadIdx.x;
    const int lane  = tid & 63;
    const int w     = tid >> 6;
    const int mrow  = lane & 31;
    const int khalf = lane >> 5;
    const int node0 = blockIdx.x * 64;

    u32x4 wreg[8][4];
#pragma unroll
    for (int kst = 0; kst < 8; ++kst)
#pragma unroll
        for (int g = 0; g < 4; ++g)
            wreg[kst][g] = wih[(kst * 16 + g * 4 + w) * 64 + lane];

    float binit[4];
#pragma unroll
    for (int g = 0; g < 4; ++g) {
        int jj = g * 128 + w * 32 + mrow;
        binit[g] = b_ih[jj] + b_hh[jj];
    }

    {
        int m_st = tid >> 2, c4 = tid & 3;
        int gn = node0 + m_st; if (gn >= N) gn = N - 1;
        const u32x4* src = (const u32x4*)(x + (size_t)gn * IN);
#pragma unroll
        for (int q = 0; q < 4; ++q) {
            int kg = q * 4 + c4;
            a_buf[kg][m_st] = src[kg];
        }
    }
    __syncthreads();

    const int coff = w * 32 + mrow;
#pragma unroll 1
    for (int Mt = 0; Mt < 2; ++Mt) {
        f32x16 acc[4];
#pragma unroll
        for (int g = 0; g < 4; ++g)
#pragma unroll
            for (int r = 0; r < 16; ++r) acc[g][r] = binit[g];

#pragma unroll
        for (int kst = 0; kst < 8; ++kst) {
            bf16x8 a = __builtin_bit_cast(bf16x8, a_buf[kst * 2 + khalf][Mt * 32 + mrow]);
#pragma unroll
            for (int g = 0; g < 4; ++g)
                acc[g] = __builtin_amdgcn_mfma_f32_32x32x16_bf16(
                    a, __builtin_bit_cast(bf16x8, wreg[kst][g]), acc[g], 0, 0, 0);
        }

#pragma unroll
        for (int r = 0; r < 16; ++r) {
            int m = Mt * 32 + (r & 3) + 8 * (r >> 2) + 4 * khalf;
            u32x2 d;
            d.x = pack2bf16(acc[0][r], acc[1][r]);
            d.y = pack2bf16(acc[2][r], acc[3][r]);
            xu[(size_t)(node0 + m) * 128 + coff] = d;
        }
    }
}

// ---------- kernel B: recurrent LSTM (C^T) + fused output linear ----------
// wave w owns channels [w*16,w*16+16) of ALL 4 gates; C^T: row = channel
// (l4*4+q), col = node. Lane owns 4 ADJACENT channels of 1 node per tile ->
// shfl-free h pack. h LDS: [node][ch] bf16, row stride 272B (17x16B).
template <int NOUT, int ACT, typename OutT>
__global__ __launch_bounds__(512, 4) void k_lstm_fused(
    const u32x2*  __restrict__ xu,      // 1KB gate-quad rows
    const int*    __restrict__ nbr,     // [N,16]
    const u32x4*  __restrict__ whh,     // 128 frags (A-operand)
    const u32x4*  __restrict__ wout,    // epilogue A-frags (K=256 concat)
    const float*  __restrict__ bout,    // [NOUT]
    const ushort* __restrict__ x_in,    // [N,128] bf16 (self input)
    OutT*         __restrict__ out,     // [N,NOUT]
    int N)
{
    constexpr int HSTR = 272;                        // 17 x 16B, b128-aligned
    __shared__ alignas(16) char h_lds[2][32 * HSTR]; // 2 x 8.5KB
    __shared__ uint32_t idxs[DEG * 32];              // prescaled byte offsets

    const int tid  = threadIdx.x;
    const int lane = tid & 63;
    const int w    = tid >> 6;
    const int col  = lane & 15;
    const int l4   = lane >> 4;
    const int node0 = blockIdx.x * 32;

    {
        int m = tid & 31, t = tid >> 5;
        int gn = node0 + m; if (gn >= N) gn = N - 1;
        idxs[t * 32 + m] = (uint32_t)nbr[gn * DEG + t] << 10;
    }
    for (int i = tid; i < 32 * HSTR / 16; i += 512)
        ((u32x4*)h_lds[0])[i] = u32x4{0u, 0u, 0u, 0u};

    // W_hh A-frags: 64 regs
    u32x4 wreg[4][4];
#pragma unroll
    for (int g = 0; g < 4; ++g)
#pragma unroll
        for (int ks = 0; ks < 4; ++ks)
            wreg[g][ks] = whh[((g * 8 + w) * 4 + ks) * 64 + lane];

    float cst[8];
#pragma unroll
    for (int r = 0; r < 8; ++r) cst[r] = 0.0f;

    const char* xu_c = (const char*)xu;
    const uint32_t goff = (uint32_t)(w * 128 + l4 * 32);  // slice byte in xu row
    const int rd0 = col * HSTR + l4 * 16;                 // + ks*64 + mt*16*HSTR
    const int wr0 = col * HSTR + w * 32 + l4 * 8;         // + mt*16*HSTR

    __syncthreads();   // idxs + h(-1) zeros visible

    // prologue gather (step 0): 32B contiguous per (node, ch-quad)
    u32x4 vv[4];
    {
        const char* p0 = xu_c + idxs[col] + goff;
        const char* p1 = xu_c + idxs[16 + col] + goff;
        vv[0] = *(const u32x4*)(p0);
        vv[1] = *(const u32x4*)(p0 + 16);
        vv[2] = *(const u32x4*)(p1);
        vv[3] = *(const u32x4*)(p1 + 16);
    }

#pragma unroll 1
    for (int t = 0; t < DEG; ++t) {
        const char* hr = h_lds[t & 1];
        char*       hw = h_lds[(t + 1) & 1];

#pragma unroll
        for (int mt = 0; mt < 2; ++mt) {
            // ---- acc init: C^T element (ch = w*16+l4*4+q, node = mt*16+col)
            f32x4 acc[4];
#pragma unroll
            for (int q = 0; q < 4; ++q) {
                uint32_t px = vv[mt * 2 + (q >> 1)][(q & 1) * 2];
                uint32_t py = vv[mt * 2 + (q >> 1)][(q & 1) * 2 + 1];
                acc[0][q] = __uint_as_float(px << 16);
                acc[1][q] = __uint_as_float(px & 0xFFFF0000u);
                acc[2][q] = __uint_as_float(py << 16);
                acc[3][q] = __uint_as_float(py & 0xFFFF0000u);
            }

            // ---- prefetch next step once vv fully consumed
            if (mt == 1 && t + 1 < DEG) {
                const char* p0 = xu_c + idxs[(t + 1) * 32 + col] + goff;
                const char* p1 = xu_c + idxs[(t + 1) * 32 + 16 + col] + goff;
                vv[0] = *(const u32x4*)(p0);
                vv[1] = *(const u32x4*)(p0 + 16);
                vv[2] = *(const u32x4*)(p1);
                vv[3] = *(const u32x4*)(p1 + 16);
            }

            // ---- MFMA C^T: A = W_hh frags, B = h(t-1) from LDS
#pragma unroll
            for (int ks = 0; ks < 4; ++ks) {
                bf16x8 b = *(const bf16x8*)(hr + mt * 16 * HSTR + rd0 + ks * 64);
#pragma unroll
                for (int g = 0; g < 4; ++g)
                    acc[g] = __builtin_amdgcn_mfma_f32_16x16x32_bf16(
                        __builtin_bit_cast(bf16x8, wreg[g][ks]), b, acc[g], 0, 0, 0);
            }

            // ---- fused cell update (7 trans/elem) + shfl-free packed h write
            float hv[4];
#pragma unroll
            for (int q = 0; q < 4; ++q)
                hv[q] = cell_h(acc[0][q], acc[1][q], acc[2][q], acc[3][q],
                               cst[mt * 4 + q]);
            u32x2 hp;
            hp.x = pack2bf16(hv[0], hv[1]);
            hp.y = pack2bf16(hv[2], hv[3]);
            *(u32x2*)(hw + mt * 16 * HSTR + wr0) = hp;
        }

        __syncthreads();   // h(t) visible; WAR-safe via dbuf (1 barrier/step)
    }

    // ---- fused output linear: out = act([x|h] @ [Ws;Wn]^T + b), C^T MFMA
    {
        const char* hf = h_lds[0];                 // h(15) parity: buf[16&1]
        constexpr int TILES = (NOUT == 128) ? 2 : 1;
        const int otile = (NOUT == 128) ? w : (w & 3);
        const int mtb   = (NOUT == 128) ? 0 : (w >> 2);
        const int och0  = otile * 16 + l4 * 4;
        const float4 bq = *(const float4*)(bout + och0);

#pragma unroll
        for (int mi = 0; mi < TILES; ++mi) {
            const int mt = mtb + mi;
            const int gn = node0 + mt * 16 + col;
            const int gx = (gn < N) ? gn : (N - 1);
            f32x4 acc = {bq.x, bq.y, bq.z, bq.w};
#pragma unroll
            for (int ks = 0; ks < 8; ++ks) {
                u32x4 af = wout[(otile * 8 + ks) * 64 + lane];
                bf16x8 bf_;
                if (ks < 4)
                    bf_ = *(const bf16x8*)((const char*)x_in + (size_t)gx * 256 +
                                           ks * 64 + l4 * 16);
                else
                    bf_ = *(const bf16x8*)(hf + mt * 16 * HSTR + col * HSTR +
                                           (ks - 4) * 64 + l4 * 16);
                acc = __builtin_amdgcn_mfma_f32_16x16x32_bf16(
                    __builtin_bit_cast(bf16x8, af), bf_, acc, 0, 0, 0);
            }
            if (gn < N) {
                float av[4];
#pragma unroll
                for (int q = 0; q < 4; ++q)
                    av[q] = (ACT == 0) ? fmaxf(acc[q], 0.0f) : fsigmoid(acc[q]);
                if constexpr (sizeof(OutT) == 2) {
                    u32x2 o;
                    o.x = pack2bf16(av[0], av[1]);
                    o.y = pack2bf16(av[2], av[3]);
                    *(u32x2*)((ushort*)out + (size_t)gn * NOUT + och0) = o;
                } else {
                    f32x4 o = {av[0], av[1], av[2], av[3]};
                    *(f32x4*)((float*)out + (size_t)gn * NOUT + och0) = o;
                }
            }
        }
    }
}

extern "C" void kernel_launch(void* const* d_in, const int* in_sizes, int n_in,
                              void* d_out, int out_size, void* d_ws, size_t ws_size,
                              hipStream_t stream)
{
    const float* feats    = (const float*)d_in[0];
    const int*   nbr      = (const int*)  d_in[1];
    const float* w_ih1    = (const float*)d_in[2];
    const float* w_hh1    = (const float*)d_in[3];
    const float* b_ih1    = (const float*)d_in[4];
    const float* b_hh1    = (const float*)d_in[5];
    const float* w_self1  = (const float*)d_in[6];
    const float* w_neigh1 = (const float*)d_in[7];
    const float* b1       = (const float*)d_in[8];
    const float* w_ih2    = (const float*)d_in[9];
    const float* w_hh2    = (const float*)d_in[10];
    const float* b_ih2    = (const float*)d_in[11];
    const float* b_hh2    = (const float*)d_in[12];
    const float* w_self2  = (const float*)d_in[13];
    const float* w_neigh2 = (const float*)d_in[14];
    const float* b2       = (const float*)d_in[15];
    float* out = (float*)d_out;

    const int N = in_sizes[0] / IN;   // 50000
    const long long Nceil = (N + 63) & ~63LL;

    char* ws = (char*)d_ws;
    size_t off = 0;
    auto alloc = [&](size_t bytes) -> void* {
        void* p = (void*)(ws + off);
        off += (bytes + 255) & ~(size_t)255;
        return p;
    };
    u32x4*  wfrag_ih1 = (u32x4*)alloc(8192 * 16);
    u32x4*  wfrag_hh1 = (u32x4*)alloc(8192 * 16);
    u32x4*  wfrag_ih2 = (u32x4*)alloc(8192 * 16);
    u32x4*  wfrag_hh2 = (u32x4*)alloc(8192 * 16);
    u32x4*  wofrag1   = (u32x4*)alloc(4096 * 16);   // 64KB epilogue A-frags L1
    u32x4*  wofrag2   = (u32x4*)alloc(2048 * 16);   // 32KB epilogue A-frags L2
    ushort* feats_bf  = (ushort*)alloc((size_t)N * 128 * 2);
    ushort* out1      = (ushort*)alloc((size_t)N * 128 * 2);
    u32x2*  xu_buf    = (u32x2*)alloc((size_t)Nceil * 128 * 8);   // 51.25MB

    // prep
    k_pack_all<<<dim3(128), dim3(256), 0, stream>>>(w_ih1, wfrag_ih1, w_hh1, wfrag_hh1,
                                                    w_ih2, wfrag_ih2, w_hh2, wfrag_hh2);
    k_pack_out<<<dim3(24), dim3(256), 0, stream>>>(w_self1, w_neigh1, wofrag1,
                                                   w_self2, w_neigh2, wofrag2);
    k_cast_bf16<<<dim3((N * 128 / 4 + 255) / 256), dim3(256), 0, stream>>>(feats, feats_bf, N * 128);

    const int nblk64 = (int)(Nceil / 64);
    const int nblk32 = (N + 31) / 32;

    // layer 1
    k_xu<<<dim3(nblk64), dim3(256), 0, stream>>>(feats_bf, wfrag_ih1, b_ih1, b_hh1, xu_buf, N);
    k_lstm_fused<128, 0, ushort><<<dim3(nblk32), dim3(512), 0, stream>>>(
        xu_buf, nbr, wfrag_hh1, wofrag1, b1, feats_bf, out1, N);

    // layer 2
    k_xu<<<dim3(nblk64), dim3(256), 0, stream>>>(out1, wfrag_ih2, b_ih2, b_hh2, xu_buf, N);
    k_lstm_fused<64, 1, float><<<dim3(nblk32), dim3(512), 0, stream>>>(
        xu_buf, nbr, wfrag_hh2, wofrag2, b2, out1, out, N);
}